// Round 1
// baseline (773.667 us; speedup 1.0000x reference)
//
#include <hip/hip_runtime.h>

// Problem constants (from reference):
#define CCH 3
#define HH 224
#define WW 220
#define PH 56          // H / ROWS
#define PW 44          // W / COLS
#define ROWS 4
#define COLS 5
#define NP 20          // num patches
#define HID 32

#define W4   (WW / 4)        // 55 float4 per image row
#define HW4  (HH * WW / 4)   // 12320 float4 per channel plane
#define PW4  (PW / 4)        // 11 float4 per patch row
#define N4   (CCH * PH * PW4) // 1848 float4 per patch
#define PATCH_ELEMS 7392.0f  // C * PH * PW

__global__ __launch_bounds__(256) void patch_mlp_kernel(
    const float* __restrict__ x,
    const float* __restrict__ w1, const float* __restrict__ b1,
    const float* __restrict__ w2, const float* __restrict__ b2,
    float* __restrict__ out, int B)
{
    const int blk = blockIdx.x;
    const int b   = blk / NP;
    const int p   = blk - b * NP;
    const int pr  = p / COLS;
    const int pc  = p - pr * COLS;

    const float4* base4 = (const float4*)x
                        + (size_t)b * (size_t)(CCH * HH * WW / 4)
                        + pr * (PH * W4)
                        + pc * PW4;

    const int tid = threadIdx.x;

    // Streaming patch sum: 1848 float4 per block, ~7.2 per thread.
    float partial = 0.f;
    for (int t = tid; t < N4; t += 256) {
        int row = t / PW4;           // 0..167  (channel-row within patch)
        int col = t - row * PW4;     // 0..10
        int c   = row / PH;          // 0..2
        int r   = row - c * PH;      // 0..55
        float4 v = base4[c * HW4 + r * W4 + col];
        partial += v.x + v.y + v.z + v.w;
    }

    // Wave (64-lane) reduce, then cross-wave via LDS.
    for (int off = 32; off; off >>= 1)
        partial += __shfl_down(partial, off, 64);

    __shared__ float swarp[4];
    __shared__ float sfeat;
    const int wid = tid >> 6;
    if ((tid & 63) == 0) swarp[wid] = partial;
    __syncthreads();
    if (tid == 0) {
        float tot = swarp[0] + swarp[1] + swarp[2] + swarp[3];
        sfeat = tot / PATCH_ELEMS;   // patch mean
    }
    __syncthreads();

    // Per-patch scalar MLP: relu(f*w1 + b1) . w2 + b2, on wave 0.
    if (tid < 64) {
        const float f = sfeat;
        float term = 0.f;
        if (tid < HID) {
            float h = fmaf(f, w1[p * HID + tid], b1[p * HID + tid]);
            term = fmaxf(h, 0.f) * w2[p * HID + tid];
        }
        for (int off = 32; off; off >>= 1)
            term += __shfl_down(term, off, 64);
        if (tid == 0)
            out[B + (size_t)b * NP + p] = term + b2[p];  // contribs tail
    }
}

__global__ __launch_bounds__(256) void score_kernel(
    const float* __restrict__ contribs, float* __restrict__ score, int B)
{
    int b = blockIdx.x * blockDim.x + threadIdx.x;
    if (b < B) {
        float s = 0.f;
        #pragma unroll
        for (int p = 0; p < NP; p++)
            s += contribs[(size_t)b * NP + p];
        score[b] = s;
    }
}

extern "C" void kernel_launch(void* const* d_in, const int* in_sizes, int n_in,
                              void* d_out, int out_size, void* d_ws, size_t ws_size,
                              hipStream_t stream)
{
    const float* x  = (const float*)d_in[0];
    const float* w1 = (const float*)d_in[1];
    const float* b1 = (const float*)d_in[2];
    const float* w2 = (const float*)d_in[3];
    const float* b2 = (const float*)d_in[4];
    float* out = (float*)d_out;

    const int B = in_sizes[0] / (CCH * HH * WW);  // 1024

    patch_mlp_kernel<<<B * NP, 256, 0, stream>>>(x, w1, b1, w2, b2, out, B);
    score_kernel<<<(B + 255) / 256, 256, 0, stream>>>(out + B, out, B);
}

// Round 2
// 762.769 us; speedup vs baseline: 1.0143x; 1.0143x over previous
//
#include <hip/hip_runtime.h>

// Problem constants (from reference):
#define CCH 3
#define HH 224
#define WW 220
#define ROWS 4
#define COLS 5
#define NP 20          // num patches
#define HID 32
#define PH 56          // H / ROWS
#define PW 44          // W / COLS

#define W4      (WW / 4)             // 55 float4 per image row
#define IMG4    (CCH * HH * W4)      // 36960 float4 per image
#define INV_N   (1.0f / 7392.0f)     // 1 / (C*PH*PW)

// One block per image. Lanes 0..54 of each wave load one full 880B image row
// (perfectly coalesced float4). Lane's patch-column pc = lane/11 is static;
// each lane keeps 4 register partials (one per patch-row pr). Wave w handles
// rows r = 4*j + w within each pr band; the pr-unrolled inner loop keeps 4
// independent loads in flight per wave.
__global__ __launch_bounds__(256) void fused_patch_nam_kernel(
    const float* __restrict__ x,
    const float* __restrict__ w1, const float* __restrict__ b1,
    const float* __restrict__ w2, const float* __restrict__ b2,
    float* __restrict__ out, int B)
{
    const int b    = blockIdx.x;
    const int tid  = threadIdx.x;
    const int wid  = tid >> 6;      // wave 0..3
    const int lane = tid & 63;      // 0..63; 55..63 idle on loads

    const float4* img4 = (const float4*)x + (size_t)b * IMG4;

    float part[ROWS] = {0.f, 0.f, 0.f, 0.f};

    if (lane < W4) {
        for (int c = 0; c < CCH; ++c) {
            const float4* pbase = img4 + (size_t)(c * HH + wid) * W4 + lane;
            for (int j = 0; j < PH / 4; ++j) {           // 14 row-groups
                const float4* rb = pbase + (j * 4) * W4;
                #pragma unroll
                for (int pr = 0; pr < ROWS; ++pr) {
                    float4 v = rb[pr * PH * W4];         // rows 0/56/112/168 apart
                    part[pr] += (v.x + v.y) + (v.z + v.w);
                }
            }
        }
    }

    // Stash per-lane partials: [wave][pr][lane]
    __shared__ float red[4][ROWS][W4 + 1];
    if (lane < W4) {
        #pragma unroll
        for (int pr = 0; pr < ROWS; ++pr)
            red[wid][pr][lane] = part[pr];
    }
    __syncthreads();

    __shared__ float contribs_s[NP];
    if (tid < NP) {
        const int pr = tid / COLS;
        const int pc = tid - pr * COLS;
        float s = 0.f;
        #pragma unroll
        for (int w = 0; w < 4; ++w)
            #pragma unroll
            for (int l = 0; l < W4 / COLS; ++l)          // 11 lanes per pc
                s += red[w][pr][pc * (W4 / COLS) + l];
        const float f = s * INV_N;                        // patch mean

        // scalar MLP: relu(f*w1 + b1) . w2 + b2
        float acc = 0.f;
        #pragma unroll
        for (int k = 0; k < HID; ++k) {
            float h = fmaf(f, w1[tid * HID + k], b1[tid * HID + k]);
            acc = fmaf(fmaxf(h, 0.f), w2[tid * HID + k], acc);
        }
        const float contrib = acc + b2[tid];
        out[B + (size_t)b * NP + tid] = contrib;          // contribs tail
        contribs_s[tid] = contrib;
    }
    __syncthreads();

    if (tid == 0) {
        float s = 0.f;
        #pragma unroll
        for (int p = 0; p < NP; ++p) s += contribs_s[p];
        out[b] = s;                                       // score head
    }
}

extern "C" void kernel_launch(void* const* d_in, const int* in_sizes, int n_in,
                              void* d_out, int out_size, void* d_ws, size_t ws_size,
                              hipStream_t stream)
{
    const float* x  = (const float*)d_in[0];
    const float* w1 = (const float*)d_in[1];
    const float* b1 = (const float*)d_in[2];
    const float* w2 = (const float*)d_in[3];
    const float* b2 = (const float*)d_in[4];
    float* out = (float*)d_out;

    const int B = in_sizes[0] / (CCH * HH * WW);  // 1024

    fused_patch_nam_kernel<<<B, 256, 0, stream>>>(x, w1, b1, w2, b2, out, B);
}

// Round 3
// 731.902 us; speedup vs baseline: 1.0571x; 1.0422x over previous
//
#include <hip/hip_runtime.h>

// Problem constants (from reference):
#define CCH 3
#define HH 224
#define WW 220
#define ROWS 4
#define COLS 5
#define NP 20          // num patches
#define HID 32
#define PH 56          // H / ROWS
#define PW 44          // W / COLS

#define W4      (WW / 4)             // 55 float4 per image row
#define IMG4    (CCH * HH * W4)      // 36960 float4 per image
#define LPP     (W4 / COLS)          // 11 float4-lanes per patch column
#define INV_N   (1.0f / 7392.0f)     // 1 / (C*PH*PW)

#define NWAVES  8                    // 512 threads = 8 waves
#define JITER   (PH / NWAVES)        // 7 row-groups per wave per band

typedef float v4f __attribute__((ext_vector_type(4)));

// One block per image, 512 threads (8 waves → 4 blocks/CU = 32 waves/CU, full
// occupancy). Lanes 0..54 of each wave load one full 880B image row (perfectly
// coalesced float4, non-temporal: x >> L3, zero reuse). Lane's patch-column
// pc = lane/11 is static; each lane keeps 4 register partials (one per
// patch-row band pr). Wave w handles rows r = 8*j + w within each band; the
// pr-unrolled inner loop keeps 4 independent loads in flight per wave.
__global__ __launch_bounds__(512) void fused_patch_nam_kernel(
    const float* __restrict__ x,
    const float* __restrict__ w1, const float* __restrict__ b1,
    const float* __restrict__ w2, const float* __restrict__ b2,
    float* __restrict__ out, int B)
{
    const int b    = blockIdx.x;
    const int tid  = threadIdx.x;
    const int wid  = tid >> 6;      // wave 0..7
    const int lane = tid & 63;      // 0..63; 55..63 idle on loads

    const v4f* img4 = (const v4f*)x + (size_t)b * IMG4;

    float part[ROWS] = {0.f, 0.f, 0.f, 0.f};

    if (lane < W4) {
        for (int c = 0; c < CCH; ++c) {
            const v4f* pbase = img4 + (size_t)(c * HH + wid) * W4 + lane;
            #pragma unroll
            for (int j = 0; j < JITER; ++j) {            // rows w, w+8, ... w+48
                const v4f* rb = pbase + (j * NWAVES) * W4;
                #pragma unroll
                for (int pr = 0; pr < ROWS; ++pr) {
                    v4f v = __builtin_nontemporal_load(rb + pr * PH * W4);
                    part[pr] += (v.x + v.y) + (v.z + v.w);
                }
            }
        }
    }

    // Stash per-lane partials: [wave][pr][lane]
    __shared__ float red[NWAVES][ROWS][W4 + 1];
    if (lane < W4) {
        #pragma unroll
        for (int pr = 0; pr < ROWS; ++pr)
            red[wid][pr][lane] = part[pr];
    }
    __syncthreads();

    __shared__ float contribs_s[NP];
    if (tid < NP) {
        const int pr = tid / COLS;
        const int pc = tid - pr * COLS;
        float s = 0.f;
        #pragma unroll
        for (int w = 0; w < NWAVES; ++w)
            #pragma unroll
            for (int l = 0; l < LPP; ++l)                // 11 lanes per pc
                s += red[w][pr][pc * LPP + l];
        const float f = s * INV_N;                        // patch mean

        // scalar MLP: relu(f*w1 + b1) . w2 + b2
        float acc = 0.f;
        #pragma unroll
        for (int k = 0; k < HID; ++k) {
            float h = fmaf(f, w1[tid * HID + k], b1[tid * HID + k]);
            acc = fmaf(fmaxf(h, 0.f), w2[tid * HID + k], acc);
        }
        const float contrib = acc + b2[tid];
        out[B + (size_t)b * NP + tid] = contrib;          // contribs tail
        contribs_s[tid] = contrib;
    }
    __syncthreads();

    if (tid == 0) {
        float s = 0.f;
        #pragma unroll
        for (int p = 0; p < NP; ++p) s += contribs_s[p];
        out[b] = s;                                       // score head
    }
}

extern "C" void kernel_launch(void* const* d_in, const int* in_sizes, int n_in,
                              void* d_out, int out_size, void* d_ws, size_t ws_size,
                              hipStream_t stream)
{
    const float* x  = (const float*)d_in[0];
    const float* w1 = (const float*)d_in[1];
    const float* b1 = (const float*)d_in[2];
    const float* w2 = (const float*)d_in[3];
    const float* b2 = (const float*)d_in[4];
    float* out = (float*)d_out;

    const int B = in_sizes[0] / (CCH * HH * WW);  // 1024

    fused_patch_nam_kernel<<<B, 512, 0, stream>>>(x, w1, b1, w2, b2, out, B);
}